// Round 4
// baseline (3927.308 us; speedup 1.0000x reference)
//
#include <hip/hip_runtime.h>
#include <stdint.h>

// GRU acoustic model, fp32 I/O. R13: address hoisting + chain split.
// R12 post-mortem: 16-wave/1-slice layout landed 2517us (step 2950 cyc);
// per-CU MfmaUtil 46% (~1360 cyc matrix) but VALUBusy 47% (~1390 cyc) --
// ~2x the algorithmic tail. Excess = per-step recomputed LDS addressing
// (A-chunk swizzle selects, wl4/wlB/wxE bases, h-write swizzle) + waves
// 0-2 re-reading A for the extra slice + 5-deep dependent MFI8 chains.
// R13 (bit-identical math):
//  (1) o^(rr<<4) == kt*64 + ((q^rr)<<4) -> one per-lane A base per phase
//      + offset: immediates; zero lanes point into a 320B zero pad.
//      2-phase unrolled loop; ALL LDS pointers hoisted as named constants.
//  (2) waves 0-2 reuse the 5 A-chunk registers for the extra slice; ebE
//      biases hoisted to registers.
//  (3) accumulator chains split kt{0-2}/{3-4}, exact int add of elem 0:
//      dependent-MFMA depth 5 -> 3.
// Decoder unchanged (proven R2-R12).
#define FEAT 13
#define EMB 300
#define BATCH 64
#define TSTEPS 2048
#define ROWS 4              // valid batch rows per WG
#define HSTR 320            // hbuf row stride, bytes (20 granules of 16)
#define QW  2199.7045f      // 127*sqrt(300)
#define SWH 3.5795795e-6f   // 1/(127*127*sqrt(300))

typedef float  floatx4 __attribute__((ext_vector_type(4)));
typedef short  shortx8 __attribute__((ext_vector_type(8)));
typedef int    intx4   __attribute__((ext_vector_type(4)));

__device__ __forceinline__ uint16_t f2b(float f) {
  union { float f; uint32_t i; } c; c.f = f;
  uint32_t r = c.i + 0x7fffu + ((c.i >> 16) & 1u);
  return (uint16_t)(r >> 16);
}
__device__ __forceinline__ float sigf(float x) {
  return __builtin_amdgcn_rcpf(1.f + __expf(-x));
}
__device__ __forceinline__ float tanhf_(float x) {
  return 1.f - 2.f * __builtin_amdgcn_rcpf(1.f + __expf(2.f * x));
}
__device__ __forceinline__ int q8w(float v) {
  return __float2int_rn(fminf(fmaxf(v * QW, -127.f), 127.f));
}

// Raw barrier: LDS-order only (no vmcnt drain; wave 15's global x loads
// stay in flight across it).
__device__ __forceinline__ void barx() {
  asm volatile("s_waitcnt lgkmcnt(0)" ::: "memory");
  __builtin_amdgcn_s_barrier();
  asm volatile("" ::: "memory");
}

#define MFI8(A, B, C) __builtin_amdgcn_mfma_i32_16x16x64_i8(A, B, C, 0, 0, 0)
#define MFBF(A, B, C) __builtin_amdgcn_mfma_f32_16x16x32_bf16(A, B, C, 0, 0, 0)

__launch_bounds__(1024, 4)
__global__ void gru_enc(const float* __restrict__ x,     // [64][2048][13]
                        const float* __restrict__ eWih,  // [900][13]
                        const float* __restrict__ eWhh,  // [900][300]
                        const float* __restrict__ ebih,  // [900]
                        const float* __restrict__ ebhh,  // [900]
                        const float* __restrict__ fcW,   // [300][300]
                        const float* __restrict__ fcb,   // [300]
                        float* __restrict__ out) {
  // hb: element (row r, col c) at byte r*HSTR + (c ^ (r<<4)); since c's
  // bits 4-5 hold (c>>4)&3 and r<4, the XOR flattens to
  //   r*HSTR + ((q^r)<<4) + kt*64   for c = kt*64 + q*16 + nl.
  __shared__ __align__(16) signed char hb[2][ROWS][HSTR];     // 2560 B
  __shared__ __align__(16) signed char zpad[HSTR];            // zero region
  __shared__ __align__(16) uint16_t    xt[2][16][32];         // 2048 B
  __shared__ __align__(16) signed char wl4[16][3][1024];      // 49152 B
  __shared__ __align__(16) signed char wlB[3][3][5][1024];    // 46080 B
  __shared__ __align__(16) uint16_t    wxE[3][3][64][8];      // 9216 B
  __shared__ __align__(16) floatx4     ebE[3][16];            // 768 B

  const int tid = threadIdx.x, lane = tid & 63, w = tid >> 6;   // w in [0,16)
  const int nl = lane & 15, q = lane >> 4;
  const int g = blockIdx.x;          // batch rows 4g..4g+3

  // ---- preamble: own slice w -> regs (kt 0-3) + wl4 (kt 4) ----
  intx4   Bh[3][4];
  shortx8 Bx[3];
  float bS0, bS1, bHN, bIN;
  {
    const int jj = 16 * w + nl;            // <= 255+15 < EMB: always valid
#pragma unroll
    for (int gt = 0; gt < 3; ++gt) {
      const int R = gt * EMB + jj;
      for (int kt = 0; kt < 5; ++kt) {
        int bb[4] = {0, 0, 0, 0};
        for (int e = 0; e < 16; ++e) {
          int kk = kt * 64 + q * 16 + e;
          float v = (kk < EMB) ? eWhh[(size_t)R * EMB + kk] : 0.f;
          bb[e >> 2] |= (q8w(v) & 255) << ((e & 3) * 8);
        }
        intx4 t4; t4[0] = bb[0]; t4[1] = bb[1]; t4[2] = bb[2]; t4[3] = bb[3];
        if (kt < 4) Bh[gt][kt] = t4;
        else        *(intx4*)&wl4[w][gt][lane * 16] = t4;
      }
      union { uint16_t u[8]; shortx8 v; } c;
      for (int e = 0; e < 8; ++e) {
        int kk = q * 8 + e;
        c.u[e] = (kk < FEAT) ? f2b(eWih[R * FEAT + kk]) : (uint16_t)0;
      }
      Bx[gt] = c.v;
    }
    bS0 = ebih[jj] + ebhh[jj];
    bS1 = ebih[EMB + jj] + ebhh[EMB + jj];
    bHN = ebhh[2 * EMB + jj];
    bIN = ebih[2 * EMB + jj];
  }
  // ---- extra slices 16-18: Whh blocks filled by waves 7-15 ----
  if (w >= 7) {
    const int u = w - 7, eI = u / 3, gt = u - 3 * eI;
    const int jj = 16 * (16 + eI) + nl;
    const bool jvv = (jj < EMB);
    const int R = gt * EMB + (jvv ? jj : 0);
    for (int kt = 0; kt < 5; ++kt) {
      int bb[4] = {0, 0, 0, 0};
      for (int e = 0; e < 16; ++e) {
        int kk = kt * 64 + q * 16 + e;
        float v = (jvv && kk < EMB) ? eWhh[(size_t)R * EMB + kk] : 0.f;
        bb[e >> 2] |= (q8w(v) & 255) << ((e & 3) * 8);
      }
      intx4 t4; t4[0] = bb[0]; t4[1] = bb[1]; t4[2] = bb[2]; t4[3] = bb[3];
      *(intx4*)&wlB[eI][gt][kt][lane * 16] = t4;
    }
  }
  // ---- extra slices' Wih fragments (waves 3-5) ----
  if (w >= 3 && w < 6) {
    const int eI = w - 3;
    const int jj = 16 * (16 + eI) + nl;
    const bool jvv = (jj < EMB);
    const int R0 = jvv ? jj : 0;
#pragma unroll
    for (int gt = 0; gt < 3; ++gt) {
      union { uint16_t u[8]; shortx8 v; } c;
      for (int e = 0; e < 8; ++e) {
        int kk = q * 8 + e;
        c.u[e] = (jvv && kk < FEAT)
                     ? f2b(eWih[(size_t)(gt * EMB + R0) * FEAT + kk])
                     : (uint16_t)0;
      }
      *(shortx8*)&wxE[eI][gt][lane][0] = c.v;
    }
  }
  // ---- extra slices' biases (wave 6) ----
  if (w == 6 && lane < 48) {
    const int eI = lane >> 4, j2 = lane & 15;
    const int jj = 16 * (16 + eI) + j2;
    const bool jvv = (jj < EMB);
    floatx4 v;
    v[0] = jvv ? (ebih[jj] + ebhh[jj]) : 0.f;
    v[1] = jvv ? (ebih[EMB + jj] + ebhh[EMB + jj]) : 0.f;
    v[2] = jvv ? ebhh[2 * EMB + jj] : 0.f;
    v[3] = jvv ? ebih[2 * EMB + jj] : 0.f;
    ebE[eI][j2] = v;
  }

  // ---- init LDS: zero h/x buffers + zero pad, then stage x_0 ----
  for (int i = tid; i < 2 * ROWS * HSTR; i += 1024) ((signed char*)hb)[i] = 0;
  for (int i = tid; i < HSTR; i += 1024) zpad[i] = 0;
  for (int i = tid; i < 2 * 16 * 32; i += 1024) ((uint16_t*)xt)[i] = 0;
  __syncthreads();
  if (tid < ROWS * FEAT) {
    int m = tid / FEAT, f = tid - m * FEAT;
    xt[0][4 * m][f] = f2b(x[((size_t)(g * ROWS + m) * TSTEPS) * FEAT + f]);
  }
  __syncthreads();

  // ---- hoisted loop-invariant state ----
  const int rr_ = nl >> 2;               // A-side batch row (if nl%4==0)
  const bool areal = ((nl & 3) == 0);
  const floatx4 zf4 = {0.f, 0.f, 0.f, 0.f};
  const intx4   z4i = {0, 0, 0, 0};

  // A-read bases (phase 0 reads hb[0], phase 1 reads hb[1])
  const signed char* aB0 =
      areal ? (&hb[0][0][0] + rr_ * HSTR + ((q ^ rr_) << 4)) : zpad;
  const signed char* aB1 = areal ? (aB0 + ROWS * HSTR) : zpad;
  // x-read bases
  const uint16_t* xr0 = &xt[0][nl][q * 8];
  const uint16_t* xr1 = xr0 + 16 * 32;
  // h-write addresses (hw0 -> hb[0], hw1 -> hb[1])
  const int cown = 16 * w + nl;
  signed char* hw0 = &hb[0][q][0] + (cown ^ (q << 4));
  signed char* hw1 = hw0 + ROWS * HSTR;
  const int cext = 16 * (16 + (w < 3 ? w : 0)) + nl;
  signed char* hwE0 = &hb[0][q][0] + (cext ^ (q << 4));
  signed char* hwE1 = hwE0 + ROWS * HSTR;
  // B-operand LDS bases (offset immediates cover gt/kt)
  const signed char* wb4 = &wl4[w][0][lane * 16];
  const signed char* wbB = &wlB[w < 3 ? w : 0][0][0][lane * 16];
  const uint16_t*    wxb = &wxE[w < 3 ? w : 0][0][lane][0];
  const floatx4 ebv = (w < 3) ? ebE[w][nl] : zf4;

  // ---- x prefetch pipeline (wave 15, SIMD3) ----
  const bool xl = (w == 15) && (lane < ROWS * FEAT);
  const int xm = lane / FEAT, xf = lane - xm * FEAT;
  const float* xbase = x + ((size_t)(g * ROWS + xm) * TSTEPS) * FEAT + xf;
  float xcur = 0.f;                      // x_t, staged bottom of iter t
  if (xl) xcur = xbase[FEAT];            // x_1
  const float* xnq = xbase + 2 * FEAT;   // next load: x_2
  uint16_t* xw0 = &xt[0][4 * xm][xf];
  uint16_t* xw1 = xw0 + 16 * 32;

  float hprev = 0.f, hpE = 0.f;

  // one recurrence step; all pointers are hoisted per-phase constants
  auto STEP = [&](const signed char* aB, const uint16_t* xr,
                  signed char* hw, signed char* hwE, uint16_t* xw, int tc) {
    float xnxt = 0.f;
    if (xl && tc < TSTEPS - 1) { xnxt = *xnq; xnq += FEAT; }

    const intx4 Ah0 = *(const intx4*)(aB);
    const intx4 Ah1 = *(const intx4*)(aB + 64);
    const intx4 Ah2 = *(const intx4*)(aB + 128);
    const intx4 Ah3 = *(const intx4*)(aB + 192);
    const intx4 Ah4 = *(const intx4*)(aB + 256);
    const shortx8 Ax = *(const shortx8*)xr;

    // own slice: split chains (depth 3+2), exact int add at the end
    intx4 aRa = z4i, aZa = z4i, aNa = z4i;
    intx4 aRb = z4i, aZb = z4i, aNb = z4i;
    aRa = MFI8(Ah0, Bh[0][0], aRa);
    aZa = MFI8(Ah0, Bh[1][0], aZa);
    aNa = MFI8(Ah0, Bh[2][0], aNa);
    aRa = MFI8(Ah1, Bh[0][1], aRa);
    aZa = MFI8(Ah1, Bh[1][1], aZa);
    aNa = MFI8(Ah1, Bh[2][1], aNa);
    aRa = MFI8(Ah2, Bh[0][2], aRa);
    aZa = MFI8(Ah2, Bh[1][2], aZa);
    aNa = MFI8(Ah2, Bh[2][2], aNa);
    aRb = MFI8(Ah3, Bh[0][3], aRb);
    aZb = MFI8(Ah3, Bh[1][3], aZb);
    aNb = MFI8(Ah3, Bh[2][3], aNb);
    {
      const intx4 W40 = *(const intx4*)(wb4);
      const intx4 W41 = *(const intx4*)(wb4 + 1024);
      const intx4 W42 = *(const intx4*)(wb4 + 2048);
      aRb = MFI8(Ah4, W40, aRb);
      aZb = MFI8(Ah4, W41, aZb);
      aNb = MFI8(Ah4, W42, aNb);
    }
    const floatx4 xR = MFBF(Ax, Bx[0], zf4);
    const floatx4 xZ = MFBF(Ax, Bx[1], zf4);
    const floatx4 xN = MFBF(Ax, Bx[2], zf4);
    {
      float r  = sigf((float)(aRa[0] + aRb[0]) * SWH + xR[0] + bS0);
      float z  = sigf((float)(aZa[0] + aZb[0]) * SWH + xZ[0] + bS1);
      float hn = (float)(aNa[0] + aNb[0]) * SWH + bHN;
      float n  = tanhf_(xN[0] + bIN + r * hn);
      float h  = z * (hprev - n) + n;
      hprev = h;
      float hq = fminf(fmaxf(h * 127.f, -127.f), 127.f);
      *hw = (signed char)__float2int_rn(hq);
    }

    if (w < 3) {   // extra slice 16+w: reuse Ah0-4 registers, B from LDS
      intx4 eRa = z4i, eZa = z4i, eNa = z4i;
      intx4 eRb = z4i, eZb = z4i, eNb = z4i;
      eRa = MFI8(Ah0, *(const intx4*)(wbB), eRa);
      eZa = MFI8(Ah0, *(const intx4*)(wbB + 5120), eZa);
      eNa = MFI8(Ah0, *(const intx4*)(wbB + 10240), eNa);
      eRa = MFI8(Ah1, *(const intx4*)(wbB + 1024), eRa);
      eZa = MFI8(Ah1, *(const intx4*)(wbB + 6144), eZa);
      eNa = MFI8(Ah1, *(const intx4*)(wbB + 11264), eNa);
      eRa = MFI8(Ah2, *(const intx4*)(wbB + 2048), eRa);
      eZa = MFI8(Ah2, *(const intx4*)(wbB + 7168), eZa);
      eNa = MFI8(Ah2, *(const intx4*)(wbB + 12288), eNa);
      eRb = MFI8(Ah3, *(const intx4*)(wbB + 3072), eRb);
      eZb = MFI8(Ah3, *(const intx4*)(wbB + 8192), eZb);
      eNb = MFI8(Ah3, *(const intx4*)(wbB + 13312), eNb);
      eRb = MFI8(Ah4, *(const intx4*)(wbB + 4096), eRb);
      eZb = MFI8(Ah4, *(const intx4*)(wbB + 9216), eZb);
      eNb = MFI8(Ah4, *(const intx4*)(wbB + 14336), eNb);
      const floatx4 yR = MFBF(Ax, *(const shortx8*)(wxb), zf4);
      const floatx4 yZ = MFBF(Ax, *(const shortx8*)(wxb + 512), zf4);
      const floatx4 yN = MFBF(Ax, *(const shortx8*)(wxb + 1024), zf4);
      float r  = sigf((float)(eRa[0] + eRb[0]) * SWH + yR[0] + ebv[0]);
      float z  = sigf((float)(eZa[0] + eZb[0]) * SWH + yZ[0] + ebv[1]);
      float hn = (float)(eNa[0] + eNb[0]) * SWH + ebv[2];
      float n  = tanhf_(yN[0] + ebv[3] + r * hn);
      float h  = z * (hpE - n) + n;
      hpE = h;
      float hq = fminf(fmaxf(h * 127.f, -127.f), 127.f);
      *hwE = (signed char)__float2int_rn(hq);
    }
    // wave 15: stage x_t (loaded last iter -> a full step of vmcnt slack)
    if (xl && tc < TSTEPS) *xw = f2b(xcur);

    barx();   // h_t + x_t visible; hb double-buffered
    xcur = xnxt;
  };

  // ================= recurrence: 2 phases per iteration =================
  for (int t = 1; t <= TSTEPS; t += 2) {
    STEP(aB0, xr0, hw1, hwE1, xw1, t);       // p=0 -> pn=1
    STEP(aB1, xr1, hw0, hwE0, xw0, t + 1);   // p=1 -> pn=0
  }

  // ================= fc: emb = relu(h_T @ fcW^T + fcb) =================
  {
    float* oemb = out + (size_t)BATCH * TSTEPS * FEAT;
    intx4 AhT[5];
#pragma unroll
    for (int kt = 0; kt < 5; ++kt)   // T even -> final h in hb[0]
      AhT[kt] = *(const intx4*)(aB0 + kt * 64);
#pragma unroll
    for (int u = 0; u < 2; ++u) {
      const int s = w + 16 * u;
      if (s < 19) {   // wave-uniform
        const int jj = 16 * s + nl;
        const bool jvv = (jj < EMB);
        intx4 acc = {0, 0, 0, 0};
        for (int kt = 0; kt < 5; ++kt) {
          int bb[4] = {0, 0, 0, 0};
          for (int e = 0; e < 16; ++e) {
            int kk = kt * 64 + q * 16 + e;
            float v = (jvv && kk < EMB) ? fcW[(size_t)jj * EMB + kk] : 0.f;
            bb[e >> 2] |= (q8w(v) & 255) << ((e & 3) * 8);
          }
          intx4 b4; b4[0] = bb[0]; b4[1] = bb[1]; b4[2] = bb[2]; b4[3] = bb[3];
          acc = MFI8(AhT[kt], b4, acc);
        }
        if (jvv) {  // reg 0 = (batch row q, col jj)
          float e2 = (float)acc[0] * SWH + fcb[jj];
          oemb[(size_t)(g * ROWS + q) * EMB + jj] = e2 > 0.f ? e2 : 0.f;
        }
      }
    }
  }
}

// ---------------- decoder: 1 wave per batch, all fp32 (proven) --------------
__launch_bounds__(64, 1)
__global__ void gru_dec(const float* __restrict__ dWih,  // [39][300]
                        const float* __restrict__ dWhh,  // [39][13]
                        const float* __restrict__ dbih,  // [39]
                        const float* __restrict__ dbhh,  // [39]
                        float* __restrict__ out) {
  const int b  = blockIdx.x;
  const int lj = threadIdx.x;            // [0,13)=r [13,26)=z [26,39)=n
  const float* emb = out + (size_t)BATCH * TSTEPS * FEAT + (size_t)b * EMB;

  float Wd[FEAT];
#pragma unroll
  for (int k = 0; k < FEAT; ++k) Wd[k] = 0.f;
  float bhhv = 0.f, dgi = 0.f;
  if (lj < 3 * FEAT) {
#pragma unroll
    for (int k = 0; k < FEAT; ++k) Wd[k] = dWhh[lj * FEAT + k];
    bhhv = dbhh[lj];
    dgi  = dbih[lj];
#pragma unroll 4
    for (int k = 0; k < EMB; ++k)
      dgi = fmaf(emb[k], dWih[lj * EMB + k], dgi);
  }

  float hrep[FEAT];
#pragma unroll
  for (int k = 0; k < FEAT; ++k) hrep[k] = 0.f;
  float hown = 0.f;
  const bool nlane = (lj >= 2 * FEAT && lj < 3 * FEAT);
  float* orow = out + (size_t)b * TSTEPS * FEAT;

  for (int t = 0; t < TSTEPS; ++t) {
    float gh = bhhv;
#pragma unroll
    for (int k = 0; k < FEAT; ++k) gh = fmaf(Wd[k], hrep[k], gh);
    float sg = sigf(dgi + gh);
    float rr = __shfl(sg, (lj - 2 * FEAT) & 63);
    float zz = __shfl(sg, (lj - FEAT) & 63);
    float nn = tanhf_(dgi + rr * gh);
    float hn = zz * (hown - nn) + nn;
    bool same = (!nlane) || (hn == hown);
    if (nlane) {
      orow[t * FEAT + (lj - 2 * FEAT)] = hn;
      hown = hn;
    }
#pragma unroll
    for (int k = 0; k < FEAT; ++k) hrep[k] = __shfl(hown, 2 * FEAT + k);
    if (__all(same)) {  // exact fp32 fixed point -> rest constant
      if (nlane) {
        for (int t2 = t + 1; t2 < TSTEPS; ++t2)
          orow[t2 * FEAT + (lj - 2 * FEAT)] = hn;
      }
      break;
    }
  }
}

extern "C" void kernel_launch(void* const* d_in, const int* in_sizes, int n_in,
                              void* d_out, int out_size, void* d_ws, size_t ws_size,
                              hipStream_t stream) {
  (void)in_sizes; (void)n_in; (void)out_size; (void)d_ws; (void)ws_size;
  const float* x    = (const float*)d_in[0];
  const float* eWih = (const float*)d_in[1];
  const float* eWhh = (const float*)d_in[2];
  const float* ebih = (const float*)d_in[3];
  const float* ebhh = (const float*)d_in[4];
  const float* fcW  = (const float*)d_in[5];
  const float* fcb  = (const float*)d_in[6];
  const float* dWih = (const float*)d_in[7];
  const float* dWhh = (const float*)d_in[8];
  const float* dbih = (const float*)d_in[9];
  const float* dbhh = (const float*)d_in[10];

  hipLaunchKernelGGL(gru_enc, dim3(BATCH / ROWS), dim3(1024), 0, stream,
                     x, eWih, eWhh, ebih, ebhh, fcW, fcb, (float*)d_out);
  hipLaunchKernelGGL(gru_dec, dim3(BATCH), dim3(64), 0, stream,
                     dWih, dWhh, dbih, dbhh, (float*)d_out);
}

// Round 5
// 3048.465 us; speedup vs baseline: 1.2883x; 1.2883x over previous
//
#include <hip/hip_runtime.h>
#include <stdint.h>

// GRU acoustic model, fp32 I/O. R14: revert enc to R12 (proven 2517us
// steady) + coalesced decoder tail-fill. R13 post-mortem: address-hoist/
// 2-phase-unroll/chain-split bundle DID cut VALU (2.95->1.78) but step
// went 2950->4070 cyc with MfmaUtil also down -> pure added stall; the
// restructure broke the compiler's R12 loop pipelining. Cause not
// isolated; reverted wholesale. This round's single change: gru_dec's
// post-convergence tail was 13 lanes x ~2000 scattered 4B stores
// (store-latency-bound, ~500us of the 3038 total). Now: h values parked
// in LDS at the exact-fp32 fixed point, all 64 lanes fill the remaining
// (T-t)*13 floats coalesced (rolling j=(j-1)%13, no runtime reg-array
// indexing). Bit-identical output. Enc kernel byte-identical to R12.
#define FEAT 13
#define EMB 300
#define BATCH 64
#define TSTEPS 2048
#define ROWS 4              // valid batch rows per WG
#define HSTR 320            // hbuf row stride, bytes (20 granules of 16)
#define QW  2199.7045f      // 127*sqrt(300)
#define SWH 3.5795795e-6f   // 1/(127*127*sqrt(300))

typedef float  floatx4 __attribute__((ext_vector_type(4)));
typedef short  shortx8 __attribute__((ext_vector_type(8)));
typedef int    intx4   __attribute__((ext_vector_type(4)));

__device__ __forceinline__ uint16_t f2b(float f) {
  union { float f; uint32_t i; } c; c.f = f;
  uint32_t r = c.i + 0x7fffu + ((c.i >> 16) & 1u);
  return (uint16_t)(r >> 16);
}
__device__ __forceinline__ float sigf(float x) {
  return __builtin_amdgcn_rcpf(1.f + __expf(-x));
}
__device__ __forceinline__ float tanhf_(float x) {
  return 1.f - 2.f * __builtin_amdgcn_rcpf(1.f + __expf(2.f * x));
}
__device__ __forceinline__ int q8w(float v) {
  return __float2int_rn(fminf(fmaxf(v * QW, -127.f), 127.f));
}

// Raw barrier: LDS-order only (no vmcnt drain; wave 15's global x loads
// stay in flight across it).
__device__ __forceinline__ void barx() {
  asm volatile("s_waitcnt lgkmcnt(0)" ::: "memory");
  __builtin_amdgcn_s_barrier();
  asm volatile("" ::: "memory");
}

#define MFI8(A, B, C) __builtin_amdgcn_mfma_i32_16x16x64_i8(A, B, C, 0, 0, 0)
#define MFBF(A, B, C) __builtin_amdgcn_mfma_f32_16x16x32_bf16(A, B, C, 0, 0, 0)

__launch_bounds__(1024, 4)
__global__ void gru_enc(const float* __restrict__ x,     // [64][2048][13]
                        const float* __restrict__ eWih,  // [900][13]
                        const float* __restrict__ eWhh,  // [900][300]
                        const float* __restrict__ ebih,  // [900]
                        const float* __restrict__ ebhh,  // [900]
                        const float* __restrict__ fcW,   // [300][300]
                        const float* __restrict__ fcb,   // [300]
                        float* __restrict__ out) {
  // hb: element (row r, col c) at byte r*HSTR + (c ^ (r<<4)) (involution;
  // logical pad granule 19 maps to the per-row never-written physical
  // granule -> reads return 0).
  __shared__ __align__(16) signed char hb[2][ROWS][HSTR];     // 2560 B
  __shared__ __align__(16) signed char zsh[16];               // zero granule
  __shared__ __align__(16) uint16_t    xt[2][16][32];         // 2048 B
  __shared__ __align__(16) signed char wl4[16][3][1024];      // 49152 B
  __shared__ __align__(16) signed char wlB[3][3][5][1024];    // 46080 B
  __shared__ __align__(16) uint16_t    wxE[3][3][64][8];      // 9216 B
  __shared__ __align__(16) floatx4     ebE[3][16];            // 768 B

  const int tid = threadIdx.x, lane = tid & 63, w = tid >> 6;   // w in [0,16)
  const int nl = lane & 15, q = lane >> 4;
  const int g = blockIdx.x;          // batch rows 4g..4g+3

  // ---- preamble: own slice w -> regs (kt 0-3) + wl4 (kt 4) ----
  intx4   Bh[3][4];
  shortx8 Bx[3];
  float bS0, bS1, bHN, bIN;
  {
    const int jj = 16 * w + nl;            // <= 255+15 < EMB: always valid
#pragma unroll
    for (int gt = 0; gt < 3; ++gt) {
      const int R = gt * EMB + jj;
      for (int kt = 0; kt < 5; ++kt) {
        int bb[4] = {0, 0, 0, 0};
        for (int e = 0; e < 16; ++e) {
          int kk = kt * 64 + q * 16 + e;
          float v = (kk < EMB) ? eWhh[(size_t)R * EMB + kk] : 0.f;
          bb[e >> 2] |= (q8w(v) & 255) << ((e & 3) * 8);
        }
        intx4 t4; t4[0] = bb[0]; t4[1] = bb[1]; t4[2] = bb[2]; t4[3] = bb[3];
        if (kt < 4) Bh[gt][kt] = t4;
        else        *(intx4*)&wl4[w][gt][lane * 16] = t4;
      }
      union { uint16_t u[8]; shortx8 v; } c;
      for (int e = 0; e < 8; ++e) {
        int kk = q * 8 + e;
        c.u[e] = (kk < FEAT) ? f2b(eWih[R * FEAT + kk]) : (uint16_t)0;
      }
      Bx[gt] = c.v;
    }
    bS0 = ebih[jj] + ebhh[jj];
    bS1 = ebih[EMB + jj] + ebhh[EMB + jj];
    bHN = ebhh[2 * EMB + jj];
    bIN = ebih[2 * EMB + jj];
  }
  // ---- extra slices 16-18: Whh blocks filled by waves 7-15 ----
  if (w >= 7) {
    const int u = w - 7, eI = u / 3, gt = u - 3 * eI;
    const int jj = 16 * (16 + eI) + nl;
    const bool jvv = (jj < EMB);
    const int R = gt * EMB + (jvv ? jj : 0);
    for (int kt = 0; kt < 5; ++kt) {
      int bb[4] = {0, 0, 0, 0};
      for (int e = 0; e < 16; ++e) {
        int kk = kt * 64 + q * 16 + e;
        float v = (jvv && kk < EMB) ? eWhh[(size_t)R * EMB + kk] : 0.f;
        bb[e >> 2] |= (q8w(v) & 255) << ((e & 3) * 8);
      }
      intx4 t4; t4[0] = bb[0]; t4[1] = bb[1]; t4[2] = bb[2]; t4[3] = bb[3];
      *(intx4*)&wlB[eI][gt][kt][lane * 16] = t4;
    }
  }
  // ---- extra slices' Wih fragments (waves 3-5) ----
  if (w >= 3 && w < 6) {
    const int eI = w - 3;
    const int jj = 16 * (16 + eI) + nl;
    const bool jvv = (jj < EMB);
    const int R0 = jvv ? jj : 0;
#pragma unroll
    for (int gt = 0; gt < 3; ++gt) {
      union { uint16_t u[8]; shortx8 v; } c;
      for (int e = 0; e < 8; ++e) {
        int kk = q * 8 + e;
        c.u[e] = (jvv && kk < FEAT)
                     ? f2b(eWih[(size_t)(gt * EMB + R0) * FEAT + kk])
                     : (uint16_t)0;
      }
      *(shortx8*)&wxE[eI][gt][lane][0] = c.v;
    }
  }
  // ---- extra slices' biases (wave 6) ----
  if (w == 6 && lane < 48) {
    const int eI = lane >> 4, j2 = lane & 15;
    const int jj = 16 * (16 + eI) + j2;
    const bool jvv = (jj < EMB);
    floatx4 v;
    v[0] = jvv ? (ebih[jj] + ebhh[jj]) : 0.f;
    v[1] = jvv ? (ebih[EMB + jj] + ebhh[EMB + jj]) : 0.f;
    v[2] = jvv ? ebhh[2 * EMB + jj] : 0.f;
    v[3] = jvv ? ebih[2 * EMB + jj] : 0.f;
    ebE[eI][j2] = v;
  }

  // ---- init LDS: zero h/x buffers + zero granule, then stage x_0 ----
  for (int i = tid; i < 2 * ROWS * HSTR; i += 1024) ((signed char*)hb)[i] = 0;
  if (tid < 16) zsh[tid] = 0;
  for (int i = tid; i < 2 * 16 * 32; i += 1024) ((uint16_t*)xt)[i] = 0;
  __syncthreads();
  if (tid < ROWS * FEAT) {
    int m = tid / FEAT, f = tid - m * FEAT;
    xt[0][4 * m][f] = f2b(x[((size_t)(g * ROWS + m) * TSTEPS) * FEAT + f]);
  }
  __syncthreads();

  // ---- x prefetch pipeline (wave 15, SIMD3) ----
  const bool xl = (w == 15) && (lane < ROWS * FEAT);
  const int xm = lane / FEAT, xf = lane - xm * FEAT;
  const float* xbase = x + ((size_t)(g * ROWS + xm) * TSTEPS) * FEAT + xf;
  float xcur = 0.f;                      // x_t, staged bottom of iter t
  if (xl) xcur = xbase[FEAT];            // x_1
  const float* xnq = xbase + 2 * FEAT;   // next load: x_2

  float hprev = 0.f, hpE = 0.f;
  const int rr_ = nl >> 2;               // A-side batch row (if nl%4==0)
  const bool areal = ((nl & 3) == 0);

  // ================= recurrence: ONE lgkm barrier/step =================
  for (int t = 1; t <= TSTEPS; ++t) {
    const int p = (t - 1) & 1, pn = t & 1;
    float xnxt = 0.f;
    if (xl && t < TSTEPS - 1) { xnxt = *xnq; xnq += FEAT; }

    const signed char* hbp = &hb[p][0][0];
    const shortx8 Ax = *(const shortx8*)&xt[p][nl][q * 8];

    // own slice: 15 MFI8 (kt<4 reg-B, kt=4 LDS-B) + 3 MFBF
    intx4 aR = {0, 0, 0, 0}, aZ = {0, 0, 0, 0}, aN = {0, 0, 0, 0};
#pragma unroll
    for (int kt = 0; kt < 4; ++kt) {
      const int o = kt * 64 + q * 16;
      const signed char* ap =
          areal ? (hbp + rr_ * HSTR + (o ^ (rr_ << 4))) : zsh;
      const intx4 Ahk = *(const intx4*)ap;
      aR = MFI8(Ahk, Bh[0][kt], aR);
      aZ = MFI8(Ahk, Bh[1][kt], aZ);
      aN = MFI8(Ahk, Bh[2][kt], aN);
    }
    {
      const int o = 256 + q * 16;
      const signed char* ap =
          areal ? (hbp + rr_ * HSTR + (o ^ (rr_ << 4))) : zsh;
      const intx4 Ahk = *(const intx4*)ap;
      aR = MFI8(Ahk, *(const intx4*)&wl4[w][0][lane * 16], aR);
      aZ = MFI8(Ahk, *(const intx4*)&wl4[w][1][lane * 16], aZ);
      aN = MFI8(Ahk, *(const intx4*)&wl4[w][2][lane * 16], aN);
    }
    {
      floatx4 zf = {0.f, 0.f, 0.f, 0.f};
      floatx4 xR = MFBF(Ax, Bx[0], zf);
      floatx4 xZ = MFBF(Ax, Bx[1], zf);
      floatx4 xN = MFBF(Ax, Bx[2], zf);
      // reg 0 = (batch row q, col 16w+nl) — gates fully in-register
      float r  = sigf((float)aR[0] * SWH + xR[0] + bS0);
      float z  = sigf((float)aZ[0] * SWH + xZ[0] + bS1);
      float hn = (float)aN[0] * SWH + bHN;
      float n  = tanhf_(xN[0] + bIN + r * hn);
      float h  = z * (hprev - n) + n;
      hprev = h;
      float hq = fminf(fmaxf(h * 127.f, -127.f), 127.f);
      const int c = 16 * w + nl;
      hb[pn][q][c ^ (q << 4)] = (signed char)__float2int_rn(hq);
    }
    if (w < 3) {   // extra slice 16+w, all operands from LDS
      intx4 aR2 = {0, 0, 0, 0}, aZ2 = {0, 0, 0, 0}, aN2 = {0, 0, 0, 0};
#pragma unroll
      for (int kt = 0; kt < 5; ++kt) {
        const int o = kt * 64 + q * 16;
        const signed char* ap =
            areal ? (hbp + rr_ * HSTR + (o ^ (rr_ << 4))) : zsh;
        const intx4 Ahk = *(const intx4*)ap;
        aR2 = MFI8(Ahk, *(const intx4*)&wlB[w][0][kt][lane * 16], aR2);
        aZ2 = MFI8(Ahk, *(const intx4*)&wlB[w][1][kt][lane * 16], aZ2);
        aN2 = MFI8(Ahk, *(const intx4*)&wlB[w][2][kt][lane * 16], aN2);
      }
      floatx4 zf = {0.f, 0.f, 0.f, 0.f};
      floatx4 xR = MFBF(Ax, *(const shortx8*)&wxE[w][0][lane][0], zf);
      floatx4 xZ = MFBF(Ax, *(const shortx8*)&wxE[w][1][lane][0], zf);
      floatx4 xN = MFBF(Ax, *(const shortx8*)&wxE[w][2][lane][0], zf);
      const floatx4 eb = ebE[w][nl];
      float r  = sigf((float)aR2[0] * SWH + xR[0] + eb[0]);
      float z  = sigf((float)aZ2[0] * SWH + xZ[0] + eb[1]);
      float hn = (float)aN2[0] * SWH + eb[2];
      float n  = tanhf_(xN[0] + eb[3] + r * hn);
      float h  = z * (hpE - n) + n;
      hpE = h;
      float hq = fminf(fmaxf(h * 127.f, -127.f), 127.f);
      const int c = 16 * (16 + w) + nl;
      hb[pn][q][c ^ (q << 4)] = (signed char)__float2int_rn(hq);
    }
    // wave 15: stage x_t (loaded last iter -> a full step of vmcnt slack)
    if (xl && t < TSTEPS) xt[pn][4 * xm][xf] = f2b(xcur);

    barx();   // h_t + x_t visible; hb double-buffered
    xcur = xnxt;
  }

  // ================= fc: emb = relu(h_T @ fcW^T + fcb) =================
  {
    float* oemb = out + (size_t)BATCH * TSTEPS * FEAT;
    intx4 AhT[5];
#pragma unroll
    for (int kt = 0; kt < 5; ++kt) {  // T even -> final h in hb[0]
      const int o = kt * 64 + q * 16;
      const signed char* ap =
          areal ? (&hb[0][0][0] + rr_ * HSTR + (o ^ (rr_ << 4))) : zsh;
      AhT[kt] = *(const intx4*)ap;
    }
#pragma unroll
    for (int u = 0; u < 2; ++u) {
      const int s = w + 16 * u;
      if (s < 19) {   // wave-uniform
        const int jj = 16 * s + nl;
        const bool jvv = (jj < EMB);
        intx4 acc = {0, 0, 0, 0};
        for (int kt = 0; kt < 5; ++kt) {
          int bb[4] = {0, 0, 0, 0};
          for (int e = 0; e < 16; ++e) {
            int kk = kt * 64 + q * 16 + e;
            float v = (jvv && kk < EMB) ? fcW[(size_t)jj * EMB + kk] : 0.f;
            bb[e >> 2] |= (q8w(v) & 255) << ((e & 3) * 8);
          }
          intx4 b4; b4[0] = bb[0]; b4[1] = bb[1]; b4[2] = bb[2]; b4[3] = bb[3];
          acc = MFI8(AhT[kt], b4, acc);
        }
        if (jvv) {  // reg 0 = (batch row q, col jj)
          float e2 = (float)acc[0] * SWH + fcb[jj];
          oemb[(size_t)(g * ROWS + q) * EMB + jj] = e2 > 0.f ? e2 : 0.f;
        }
      }
    }
  }
}

// ---------------- decoder: 1 wave per batch, all fp32 ----------------------
// R14: coalesced constant tail-fill. Recurrence + early-exit identical to
// R2-R12 (exact fp32 fixed point); only the post-convergence fill changed:
// h values parked in LDS, all 64 lanes write the remaining (T-t)*13 floats
// coalesced (64x4B contiguous per iteration, rolling j=(j-1) mod 13).
__launch_bounds__(64, 1)
__global__ void gru_dec(const float* __restrict__ dWih,  // [39][300]
                        const float* __restrict__ dWhh,  // [39][13]
                        const float* __restrict__ dbih,  // [39]
                        const float* __restrict__ dbhh,  // [39]
                        float* __restrict__ out) {
  __shared__ float hsh[FEAT];
  const int b  = blockIdx.x;
  const int lj = threadIdx.x;            // [0,13)=r [13,26)=z [26,39)=n
  const float* emb = out + (size_t)BATCH * TSTEPS * FEAT + (size_t)b * EMB;

  float Wd[FEAT];
#pragma unroll
  for (int k = 0; k < FEAT; ++k) Wd[k] = 0.f;
  float bhhv = 0.f, dgi = 0.f;
  if (lj < 3 * FEAT) {
#pragma unroll
    for (int k = 0; k < FEAT; ++k) Wd[k] = dWhh[lj * FEAT + k];
    bhhv = dbhh[lj];
    dgi  = dbih[lj];
#pragma unroll 4
    for (int k = 0; k < EMB; ++k)
      dgi = fmaf(emb[k], dWih[lj * EMB + k], dgi);
  }

  float hrep[FEAT];
#pragma unroll
  for (int k = 0; k < FEAT; ++k) hrep[k] = 0.f;
  float hown = 0.f;
  const bool nlane = (lj >= 2 * FEAT && lj < 3 * FEAT);
  float* orow = out + (size_t)b * TSTEPS * FEAT;

  for (int t = 0; t < TSTEPS; ++t) {
    float gh = bhhv;
#pragma unroll
    for (int k = 0; k < FEAT; ++k) gh = fmaf(Wd[k], hrep[k], gh);
    float sg = sigf(dgi + gh);
    float rr = __shfl(sg, (lj - 2 * FEAT) & 63);
    float zz = __shfl(sg, (lj - FEAT) & 63);
    float nn = tanhf_(dgi + rr * gh);
    float hn = zz * (hown - nn) + nn;
    bool same = (!nlane) || (hn == hown);
    if (nlane) {
      orow[t * FEAT + (lj - 2 * FEAT)] = hn;
      hown = hn;
    }
#pragma unroll
    for (int k = 0; k < FEAT; ++k) hrep[k] = __shfl(hown, 2 * FEAT + k);
    if (__all(same)) {  // exact fp32 fixed point -> rest constant
      if (nlane) hsh[lj - 2 * FEAT] = hown;
      asm volatile("s_waitcnt lgkmcnt(0)" ::: "memory");
      const int total = TSTEPS * FEAT;
      int idx = (t + 1) * FEAT + lj;
      if (idx < total) {
        int j = idx % FEAT;            // one div at entry
        for (; idx < total; idx += 64) {
          orow[idx] = hsh[j];          // 64x4B coalesced per iteration
          j = (j == 0) ? (FEAT - 1) : (j - 1);   // (j+64) mod 13
        }
      }
      break;
    }
  }
}

extern "C" void kernel_launch(void* const* d_in, const int* in_sizes, int n_in,
                              void* d_out, int out_size, void* d_ws, size_t ws_size,
                              hipStream_t stream) {
  (void)in_sizes; (void)n_in; (void)out_size; (void)d_ws; (void)ws_size;
  const float* x    = (const float*)d_in[0];
  const float* eWih = (const float*)d_in[1];
  const float* eWhh = (const float*)d_in[2];
  const float* ebih = (const float*)d_in[3];
  const float* ebhh = (const float*)d_in[4];
  const float* fcW  = (const float*)d_in[5];
  const float* fcb  = (const float*)d_in[6];
  const float* dWih = (const float*)d_in[7];
  const float* dWhh = (const float*)d_in[8];
  const float* dbih = (const float*)d_in[9];
  const float* dbhh = (const float*)d_in[10];

  hipLaunchKernelGGL(gru_enc, dim3(BATCH / ROWS), dim3(1024), 0, stream,
                     x, eWih, eWhh, ebih, ebhh, fcW, fcb, (float*)d_out);
  hipLaunchKernelGGL(gru_dec, dim3(BATCH), dim3(64), 0, stream,
                     dWih, dWhh, dbih, dbhh, (float*)d_out);
}